// Round 6
// baseline (854.110 us; speedup 1.0000x reference)
//
#include <hip/hip_runtime.h>

#define NB 64
#define NS 256
#define ND 2048
#define NH 16
#define NHD 128

typedef unsigned short ushort_t;
typedef __attribute__((ext_vector_type(8))) __bf16 bf16x8;
typedef __attribute__((ext_vector_type(4))) short shortx4;
typedef __attribute__((ext_vector_type(4))) float f32x4;
typedef __attribute__((ext_vector_type(4))) unsigned short ushortx4;

__device__ __forceinline__ unsigned short f2bf(float f) {
  union { float f; unsigned int u; } v; v.f = f;
  unsigned int r = v.u + 0x7FFFu + ((v.u >> 16) & 1u);
  return (unsigned short)(r >> 16);
}

__device__ __forceinline__ void gload16(const void* g, void* l) {
  __builtin_amdgcn_global_load_lds(
      (__attribute__((address_space(1))) void*)(void*)(g),
      (__attribute__((address_space(3))) void*)(l), 16, 0, 0);
}

__global__ void cast_f32_bf16(const float* __restrict__ in, ushort_t* __restrict__ out, long n) {
  long i = ((long)blockIdx.x * blockDim.x + threadIdx.x) * 4;
  if (i + 3 < n) {
    float4 v = *reinterpret_cast<const float4*>(in + i);
    ushortx4 o;
    o.x = f2bf(v.x); o.y = f2bf(v.y); o.z = f2bf(v.z); o.w = f2bf(v.w);
    *reinterpret_cast<ushortx4*>(out + i) = o;
  }
}

// V[b,h][s][hd] -> vT[b,h][hd][s].  Reads 16B/thread (rows, L3-resident);
// writes 8 scalar bf16 per thread, wave-coalesced along s (128B segments).
__global__ void transpose_v(const ushort_t* __restrict__ qkv_v, ushort_t* __restrict__ vt) {
  const int g = blockIdx.x * 256 + threadIdx.x;  // [0, B*H*S*16)
  const int s = g & 255;
  const int hd8 = (g >> 8) & 15;
  const int bh = g >> 12;
  const ushort_t* src = qkv_v + ((long)bh << 15) + s * 128 + hd8 * 8;
  ushortx4 v0 = *reinterpret_cast<const ushortx4*>(src);
  ushortx4 v1 = *reinterpret_cast<const ushortx4*>(src + 4);
  ushort_t* dst = vt + ((long)bh << 15) + (long)(hd8 * 8) * 256 + s;
  dst[0] = v0.x; dst[256] = v0.y; dst[512] = v0.z; dst[768] = v0.w;
  dst[1024] = v1.x; dst[1280] = v1.y; dst[1536] = v1.z; dst[1792] = v1.w;
}

// ---------------------------------------------------------------------------
// 256x256 tile GEMM (unchanged from round 5 — 1013 TF, MfmaUtil 47%).
// ---------------------------------------------------------------------------
template<int MODE>
__global__ __launch_bounds__(512, 2) void gemm256(const ushort_t* __restrict__ A,
                                                  const ushort_t* __restrict__ Bt,
                                                  float* __restrict__ Cf,
                                                  ushort_t* __restrict__ Cq,
                                                  int M, int N, int K) {
  extern __shared__ char smem[];   // 4 bufs * 32768B; A at +0 (16KB), B at +16384
  const int tid = threadIdx.x;
  const int wv = tid >> 6, lane = tid & 63;
  const int l15 = lane & 15, lg = lane >> 4;
  const int wm = wv >> 2, wn = wv & 3;     // 2 x 4 wave grid; wave tile 128x64

  const int nbn = N >> 8;
  const int nwg = (M >> 8) * nbn;
  const int bid = blockIdx.x;
  const int q8 = nwg >> 3, r8 = nwg & 7;
  const int xcd = bid & 7, lin = bid >> 3;
  const int wg = (xcd < r8 ? xcd * (q8 + 1) : r8 * (q8 + 1) + (xcd - r8) * q8) + lin;
  const int m0 = (wg / nbn) << 8;
  const int n0 = (wg % nbn) << 8;

  const int srow = wv * 16 + (lane >> 2);
  const int sce = ((lane & 3) * 8) ^ (((srow >> 1) & 3) << 3);  // elems
  const ushort_t* pa0 = A  + (long)(m0 + srow) * K + sce;
  const ushort_t* pa1 = pa0 + (long)128 * K;
  const ushort_t* pb0 = Bt + (long)(n0 + srow) * K + sce;
  const ushort_t* pb1 = pb0 + (long)128 * K;

  const int c = (lg * 16) ^ (((l15 >> 1) & 3) << 4);

  f32x4 acc[8][4] = {};
  const int nkt = K >> 5;

  bf16x8 faA[8], faB[4], fbA[8], fbB[4];

  #pragma unroll
  for (int tt = 0; tt < 3; ++tt) {
    char* d = smem + tt * 32768 + wv * 1024;
    const long ko = (long)tt * 32;
    gload16(pa0 + ko, d);
    gload16(pa1 + ko, d + 8192);
    gload16(pb0 + ko, d + 16384);
    gload16(pb1 + ko, d + 24576);
  }
  asm volatile("s_waitcnt vmcnt(8)" ::: "memory");
  __builtin_amdgcn_s_barrier();
  __builtin_amdgcn_sched_barrier(0);
  #pragma unroll
  for (int i = 0; i < 8; ++i)
    faA[i] = *reinterpret_cast<const bf16x8*>(smem + (wm * 128 + i * 16 + l15) * 64 + c);
  #pragma unroll
  for (int j = 0; j < 4; ++j)
    faB[j] = *reinterpret_cast<const bf16x8*>(smem + 16384 + (wn * 64 + j * 16 + l15) * 64 + c);
  asm volatile("s_waitcnt vmcnt(4)" ::: "memory");

#define TILE(T_, CA_, CB_, NA_, NB_)                                           \
  {                                                                            \
    const int t_ = (T_);                                                       \
    __builtin_amdgcn_s_barrier();                                              \
    asm volatile("s_waitcnt lgkmcnt(0)" ::: "memory");                         \
    __builtin_amdgcn_sched_barrier(0);                                         \
    __builtin_amdgcn_s_setprio(1);                                             \
    if (t_ + 1 < nkt) {                                                        \
      const char* rb = smem + ((t_ + 1) & 3) * 32768;                          \
      _Pragma("unroll")                                                        \
      for (int i = 0; i < 8; ++i)                                              \
        NA_[i] = *reinterpret_cast<const bf16x8*>(rb + (wm * 128 + i * 16 + l15) * 64 + c); \
      _Pragma("unroll")                                                        \
      for (int j = 0; j < 4; ++j)                                              \
        NB_[j] = *reinterpret_cast<const bf16x8*>(rb + 16384 + (wn * 64 + j * 16 + l15) * 64 + c); \
    }                                                                          \
    if (t_ + 3 < nkt) {                                                        \
      char* d = smem + ((t_ + 3) & 3) * 32768 + wv * 1024;                     \
      const long ko = (long)(t_ + 3) * 32;                                     \
      gload16(pa0 + ko, d);                                                    \
      gload16(pa1 + ko, d + 8192);                                             \
      gload16(pb0 + ko, d + 16384);                                            \
      gload16(pb1 + ko, d + 24576);                                            \
    }                                                                          \
    _Pragma("unroll")                                                          \
    for (int i = 0; i < 8; ++i)                                                \
      _Pragma("unroll")                                                        \
      for (int j = 0; j < 4; ++j)                                              \
        acc[i][j] = __builtin_amdgcn_mfma_f32_16x16x32_bf16(CA_[i], CB_[j], acc[i][j], 0, 0, 0); \
    _Pragma("unroll")                                                          \
    for (int g = 0; g < 8; ++g) {                                              \
      __builtin_amdgcn_sched_group_barrier(0x008, 4, 0);                       \
      if (g < 6) __builtin_amdgcn_sched_group_barrier(0x100, 2, 0);            \
      if (g < 4) __builtin_amdgcn_sched_group_barrier(0x010, 1, 0);            \
    }                                                                          \
    __builtin_amdgcn_s_setprio(0);                                             \
    __builtin_amdgcn_sched_barrier(0);                                         \
    if (t_ + 3 < nkt) asm volatile("s_waitcnt vmcnt(4)" ::: "memory");         \
    else              asm volatile("s_waitcnt vmcnt(0)" ::: "memory");         \
  }

  for (int t = 0; t < nkt; t += 2) {
    TILE(t,     faA, faB, fbA, fbB);
    TILE(t + 1, fbA, fbB, faA, faB);
  }
#undef TILE

  #pragma unroll
  for (int k = 0; k < 8; ++k) {
    const int mrow = m0 + wm * 128 + k * 16 + lg * 4;
    #pragma unroll
    for (int j = 0; j < 4; ++j) {
      const int n = n0 + wn * 64 + j * 16 + l15;
      #pragma unroll
      for (int r = 0; r < 4; ++r) {
        const int m = mrow + r;
        const float v = acc[k][j][r];
        if (MODE == 0) {
          Cf[(long)m * N + n] = v;
        } else {
          const int tq = n >> 11, hh = (n >> 7) & 15, hd = n & 127;
          const int b = m >> 8, s = m & 255;
          Cq[((((long)tq * NB + b) * NH + hh) * NS + s) * NHD + hd] = f2bf(v);
        }
      }
    }
  }
}

// One block per (b,h); 8 waves. Causal-balanced: wave w owns q-strips
// {w*16, 240-w*16} (5 half-tile units each vs 1..8 before). V read from
// pre-transposed vT[hd][s] with vectorized 8B loads (was 128 scalar 2B
// gathers per lane per tile).
__global__ __launch_bounds__(512) void attn_fused(const ushort_t* __restrict__ qkv,
                                                  const ushort_t* __restrict__ vT,
                                                  ushort_t* __restrict__ ctx) {
  const int bh = blockIdx.x;
  const int b = bh >> 4, h = bh & 15;
  const int wave = threadIdx.x >> 6, lane = threadIdx.x & 63;
  const int l15 = lane & 15, lg = lane >> 4;
  const long head_off = ((long)(b * NH + h)) * (NS * NHD);
  const ushort_t* Qp = qkv + head_off;
  const ushort_t* Kp = qkv + (long)NB * NH * NS * NHD + head_off;
  const ushort_t* vTp = vT + ((long)bh << 15);   // [128][256]
  const int q0[2] = { wave * 16, 240 - wave * 16 };
  const int klast[2] = { (wave * 16 + 15) >> 6, (255 - wave * 16) >> 6 };

  bf16x8 qf[2][4];
  #pragma unroll
  for (int ni = 0; ni < 2; ++ni)
    #pragma unroll
    for (int kk = 0; kk < 4; ++kk)
      qf[ni][kk] = *reinterpret_cast<const bf16x8*>(Qp + (q0[ni] + l15) * NHD + kk * 32 + lg * 8);

  f32x4 o[8][2] = {};
  float mstate[2] = {-1e30f, -1e30f};
  float lstate[2] = {0.f, 0.f};
  const float scale = 0.08838834764831845f;

  for (int kt = 0; kt <= klast[1]; ++kt) {
    const bool act0 = (kt <= klast[0]);
    f32x4 st[4][2] = {};
    #pragma unroll
    for (int kk = 0; kk < 4; ++kk) {
      bf16x8 kf[4];
      #pragma unroll
      for (int mi = 0; mi < 4; ++mi)
        kf[mi] = *reinterpret_cast<const bf16x8*>(Kp + (kt * 64 + mi * 16 + l15) * NHD + kk * 32 + lg * 8);
      #pragma unroll
      for (int mi = 0; mi < 4; ++mi) {
        st[mi][1] = __builtin_amdgcn_mfma_f32_16x16x32_bf16(kf[mi], qf[1][kk], st[mi][1], 0, 0, 0);
        if (act0)
          st[mi][0] = __builtin_amdgcn_mfma_f32_16x16x32_bf16(kf[mi], qf[0][kk], st[mi][0], 0, 0, 0);
      }
    }
    shortx4 p[4][2];
    #pragma unroll
    for (int ni = 0; ni < 2; ++ni) {
      if (ni == 0 && !act0) continue;
      const bool dom = (kt == klast[ni]);
      const int q = q0[ni] + l15;
      #pragma unroll
      for (int mi = 0; mi < 4; ++mi)
        #pragma unroll
        for (int r = 0; r < 4; ++r) {
          const int kc = kt * 64 + mi * 16 + lg * 4 + r;
          float v = st[mi][ni][r] * scale;
          if (dom && kc > q) v = -1e30f;
          st[mi][ni][r] = v;
        }
      float tmax = -1e30f;
      #pragma unroll
      for (int mi = 0; mi < 4; ++mi)
        #pragma unroll
        for (int r = 0; r < 4; ++r) tmax = fmaxf(tmax, st[mi][ni][r]);
      tmax = fmaxf(tmax, __shfl_xor(tmax, 16, 64));
      tmax = fmaxf(tmax, __shfl_xor(tmax, 32, 64));
      const float mnew = fmaxf(mstate[ni], tmax);
      const float alpha = __expf(mstate[ni] - mnew);
      float tsum = 0.f;
      #pragma unroll
      for (int mi = 0; mi < 4; ++mi)
        #pragma unroll
        for (int r = 0; r < 4; ++r) {
          const float pe = __expf(st[mi][ni][r] - mnew);
          st[mi][ni][r] = pe;
          tsum += pe;
        }
      tsum += __shfl_xor(tsum, 16, 64);
      tsum += __shfl_xor(tsum, 32, 64);
      lstate[ni] = lstate[ni] * alpha + tsum;
      mstate[ni] = mnew;
      #pragma unroll
      for (int f = 0; f < 8; ++f)
        #pragma unroll
        for (int r = 0; r < 4; ++r) o[f][ni][r] *= alpha;
      #pragma unroll
      for (int mi = 0; mi < 4; ++mi)
        #pragma unroll
        for (int r = 0; r < 4; ++r) p[mi][ni][r] = (short)f2bf(st[mi][ni][r]);
    }
    // PV: vectorized V^T loads (8B, L1-resident across waves)
    #pragma unroll
    for (int f = 0; f < 8; ++f)
      #pragma unroll
      for (int mi = 0; mi < 4; ++mi) {
        const shortx4 vt4 = *reinterpret_cast<const shortx4*>(
            vTp + (f * 16 + l15) * NS + kt * 64 + mi * 16 + lg * 4);
        o[f][1] = __builtin_amdgcn_mfma_f32_16x16x16bf16_1k(vt4, p[mi][1], o[f][1], 0, 0, 0);
        if (act0)
          o[f][0] = __builtin_amdgcn_mfma_f32_16x16x16bf16_1k(vt4, p[mi][0], o[f][0], 0, 0, 0);
      }
  }
  const float inv0 = 1.f / lstate[0], inv1 = 1.f / lstate[1];
  #pragma unroll
  for (int f = 0; f < 8; ++f)
    #pragma unroll
    for (int ni = 0; ni < 2; ++ni) {
      const float inv = ni ? inv1 : inv0;
      const int q = q0[ni] + l15;
      const int hd = f * 16 + lg * 4;
      ushortx4 ov;
      #pragma unroll
      for (int r = 0; r < 4; ++r) ov[r] = f2bf(o[f][ni][r] * inv);
      *reinterpret_cast<ushortx4*>(ctx + ((long)(b * NS + q)) * ND + h * NHD + hd) = ov;
    }
}

extern "C" void kernel_launch(void* const* d_in, const int* in_sizes, int n_in,
                              void* d_out, int out_size, void* d_ws, size_t ws_size,
                              hipStream_t stream) {
  const float* x     = (const float*)d_in[0];
  const float* w_qkv = (const float*)d_in[1];
  const float* w_o   = (const float*)d_in[2];
  char* ws = (char*)d_ws;
  if (ws_size < 369098752UL) return;
  ushort_t* xb    = (ushort_t*)(ws);            // also reused as vT after GEMM1
  ushort_t* wqkvb = (ushort_t*)(ws + 67108864L);
  ushort_t* wob   = (ushort_t*)(ws + 92274688L);
  ushort_t* qkvb  = (ushort_t*)(ws + 100663296L);
  ushort_t* ctxb  = (ushort_t*)(ws + 301989888L);
  ushort_t* vTb   = xb;  // 64 MB; xb is dead once gemm256<1> completes

  const long nx = (long)NB * NS * ND;
  const long nq = 3L * ND * ND;
  const long no = (long)ND * ND;
  cast_f32_bf16<<<dim3(nx / 1024), 256, 0, stream>>>(x, xb, nx);
  cast_f32_bf16<<<dim3(nq / 1024), 256, 0, stream>>>(w_qkv, wqkvb, nq);
  cast_f32_bf16<<<dim3(no / 1024), 256, 0, stream>>>(w_o, wob, no);

  const int lds_bytes = 4 * 32768;  // 128 KiB
  (void)hipFuncSetAttribute(reinterpret_cast<const void*>(&gemm256<1>),
                            hipFuncAttributeMaxDynamicSharedMemorySize, lds_bytes);
  (void)hipFuncSetAttribute(reinterpret_cast<const void*>(&gemm256<0>),
                            hipFuncAttributeMaxDynamicSharedMemorySize, lds_bytes);

  // qkv = x @ w_qkv^T  -> permuted bf16 [3][B][H][S][HD]
  gemm256<1><<<dim3(64 * 24), 512, lds_bytes, stream>>>(xb, wqkvb, nullptr, qkvb,
                                                        NB * NS, 3 * ND, ND);
  // V -> V^T  (xb region is dead now; vT aliases it)
  transpose_v<<<dim3(16384), 256, 0, stream>>>(qkvb + 2L * NB * NH * NS * NHD, vTb);
  // fused causal attention -> ctx bf16 [B][S][D]
  attn_fused<<<dim3(NB * NH), 512, 0, stream>>>(qkvb, vTb, ctxb);
  // out = ctx @ w_o^T  (fp32)
  gemm256<0><<<dim3(64 * 8), 512, lds_bytes, stream>>>(ctxb, wob, (float*)d_out, nullptr,
                                                       NB * NS, ND, ND);
}